// Round 6
// baseline (147.180 us; speedup 1.0000x reference)
//
#include <hip/hip_runtime.h>
#include <math.h>

#define IN_F   1024
#define OUT_F  1024
#define TASK_D 256
#define RANK   8
#define HID    64
// SCALING = ALPHA / RANK = 1.0 (identity)

typedef float vfloat4 __attribute__((ext_vector_type(4)));  // native vec for nontemporal builtins

__device__ __forceinline__ float gelu_exact(float v) {
    return 0.5f * v * (1.0f + erff(v * 0.70710678118654752f));
}

// ---------------------------------------------------------------------------
// Kernel 1: generate LoRA tables for all 4 tasks.
//   vec_a_t : [4][RANK][OUT_F]  (TRANSPOSED: a_t[t][r][o] = a[t][o][r])
//   vec_b   : [4][RANK][IN_F]
// ---------------------------------------------------------------------------
__global__ __launch_bounds__(256) void gen_kernel(
    const float* __restrict__ task_emb,
    const float* __restrict__ Wa1, const float* __restrict__ ba1,
    const float* __restrict__ Wa2, const float* __restrict__ ba2,
    const float* __restrict__ Wb1, const float* __restrict__ bb1,
    const float* __restrict__ Wb2, const float* __restrict__ bb2,
    float* __restrict__ vec_a_t, float* __restrict__ vec_b)
{
    const int gen = blockIdx.x >> 7;             // 0 -> a, 1 -> b
    const int blk = blockIdx.x & 127;
    const float* __restrict__ W1 = gen ? Wb1 : Wa1;
    const float* __restrict__ b1 = gen ? bb1 : ba1;
    const float* __restrict__ W2 = gen ? Wb2 : Wa2;
    const float* __restrict__ b2 = gen ? bb2 : ba2;

    __shared__ float hs[4][HID];
    {
        const int j = threadIdx.x >> 2;          // hidden unit 0..63
        const int t = threadIdx.x & 3;           // task 0..3
        const float4* te = (const float4*)(task_emb + t * TASK_D);
        const float4* w  = (const float4*)(W1 + j * TASK_D);
        float acc = 0.f;
        #pragma unroll
        for (int d = 0; d < TASK_D / 4; ++d) {
            float4 a = te[d], b = w[d];
            acc += a.x * b.x + a.y * b.y + a.z * b.z + a.w * b.w;
        }
        hs[t][j] = gelu_exact(acc + b1[j]);
    }
    __syncthreads();

    const int lrow = threadIdx.x >> 2;           // 0..63  (W2 row within block)
    const int q    = threadIdx.x & 3;            // quarter of 64 hidden dims
    const int o    = blk * 64 + lrow;            // W2 row 0..8191

    const float4* w2 = (const float4*)(W2 + (size_t)o * HID + q * 16);
    float acc0 = 0.f, acc1 = 0.f, acc2 = 0.f, acc3 = 0.f;
    #pragma unroll
    for (int k = 0; k < 4; ++k) {
        float4 w = w2[k];
        const int kb = q * 16 + k * 4;
        acc0 += hs[0][kb] * w.x + hs[0][kb+1] * w.y + hs[0][kb+2] * w.z + hs[0][kb+3] * w.w;
        acc1 += hs[1][kb] * w.x + hs[1][kb+1] * w.y + hs[1][kb+2] * w.z + hs[1][kb+3] * w.w;
        acc2 += hs[2][kb] * w.x + hs[2][kb+1] * w.y + hs[2][kb+2] * w.z + hs[2][kb+3] * w.w;
        acc3 += hs[3][kb] * w.x + hs[3][kb+1] * w.y + hs[3][kb+2] * w.z + hs[3][kb+3] * w.w;
    }
    #pragma unroll
    for (int off = 1; off <= 2; off <<= 1) {
        acc0 += __shfl_xor(acc0, off, 64);
        acc1 += __shfl_xor(acc1, off, 64);
        acc2 += __shfl_xor(acc2, off, 64);
        acc3 += __shfl_xor(acc3, off, 64);
    }
    if (q == 0) {
        const float bb = b2[o];
        float v[4] = { acc0 + bb, acc1 + bb, acc2 + bb, acc3 + bb };
        if (gen == 0) {
            const int oo = o >> 3, r = o & 7;    // vec_a row o -> (out oo, rank r)
            #pragma unroll
            for (int t = 0; t < 4; ++t)
                vec_a_t[t * (RANK * OUT_F) + r * OUT_F + oo] = v[t];
        } else {
            #pragma unroll
            for (int t = 0; t < 4; ++t)
                vec_b[t * (RANK * IN_F) + o] = v[t];
        }
    }
}

// ---------------------------------------------------------------------------
// Kernel 2: fused LoRA apply, phase-merged.
// 1024 blocks x 256 threads, one task per block, vec_b[t] in LDS (32 KB),
// 2 rows per wave. ALL global input loads (LDS staging, x, base_out) are
// issued before the single __syncthreads(): the barrier's vmcnt(0) drain
// overlaps every input stream; after it, phase-1 dots run from LDS/regs and
// the epilogue has base_out already in registers -> no dead-memory window.
// __launch_bounds__(256,4) caps VGPR at 128 -> 4 blocks/CU (128 KB LDS).
// ---------------------------------------------------------------------------
__global__ __launch_bounds__(256, 4) void apply_kernel(
    const float* __restrict__ x, const float* __restrict__ base_out,
    const float* __restrict__ vec_a_t, const float* __restrict__ vec_b,
    float* __restrict__ out)
{
    const int t    = blockIdx.x & 3;             // task
    const int g    = blockIdx.x >> 2;            // group within task
    const int wave = threadIdx.x >> 6;
    const int lane = threadIdx.x & 63;

    const int j    = g * 8 + wave * 2;           // row / 4
    const int row0 = t + 4 * j;
    const int row1 = row0 + 4;

    __shared__ float bs[RANK * IN_F];            // 32 KB

    // 1) staging loads (oldest in vmem queue)
    vfloat4 stage[8];
    {
        const vfloat4* src = (const vfloat4*)(vec_b + (size_t)t * (RANK * IN_F));
        #pragma unroll
        for (int i = 0; i < 8; ++i)
            stage[i] = src[threadIdx.x + 256 * i];
    }

    // 2) x loads + base_out loads (overlap staging + phase 1)
    vfloat4 xv[2][4], bo[2][4];
    {
        const float* __restrict__ xr0 = x + (size_t)row0 * IN_F;
        const float* __restrict__ xr1 = x + (size_t)row1 * IN_F;
        const float* __restrict__ br0 = base_out + (size_t)row0 * OUT_F;
        const float* __restrict__ br1 = base_out + (size_t)row1 * OUT_F;
        #pragma unroll
        for (int c = 0; c < 4; ++c) {
            const int k = c * 256 + lane * 4;
            xv[0][c] = __builtin_nontemporal_load((const vfloat4*)(xr0 + k));
            xv[1][c] = __builtin_nontemporal_load((const vfloat4*)(xr1 + k));
            bo[0][c] = __builtin_nontemporal_load((const vfloat4*)(br0 + k));
            bo[1][c] = __builtin_nontemporal_load((const vfloat4*)(br1 + k));
        }
    }

    // 3) LDS fill + barrier (drains all loads; everything overlapped)
    {
        vfloat4* dst = (vfloat4*)bs;
        #pragma unroll
        for (int i = 0; i < 8; ++i)
            dst[threadIdx.x + 256 * i] = stage[i];
    }
    __syncthreads();

    // Phase 1: chunk-outer rank dots; each ds_read_b128 feeds both rows.
    float acc[2][RANK];
    #pragma unroll
    for (int i = 0; i < 2; ++i)
        #pragma unroll
        for (int r = 0; r < RANK; ++r) acc[i][r] = 0.f;

    #pragma unroll
    for (int c = 0; c < 4; ++c) {
        const int k = c * 256 + lane * 4;
        #pragma unroll
        for (int r = 0; r < RANK; ++r) {
            const float4 bv = *(const float4*)(bs + r * IN_F + k);
            acc[0][r] += xv[0][c].x * bv.x + xv[0][c].y * bv.y
                       + xv[0][c].z * bv.z + xv[0][c].w * bv.w;
            acc[1][r] += xv[1][c].x * bv.x + xv[1][c].y * bv.y
                       + xv[1][c].z * bv.z + xv[1][c].w * bv.w;
        }
    }

    // Butterfly reduce the 16 accumulators across the wave.
    #pragma unroll
    for (int off = 32; off > 0; off >>= 1) {
        #pragma unroll
        for (int i = 0; i < 2; ++i)
            #pragma unroll
            for (int r = 0; r < RANK; ++r)
                acc[i][r] += __shfl_xor(acc[i][r], off, 64);
    }

    // Epilogue: af streamed per chunk from L2-resident vec_a_t; bo already
    // in registers; nontemporal stores.
    const float* __restrict__ at = vec_a_t + (size_t)t * (RANK * OUT_F);
    float* __restrict__ or0 = out + (size_t)row0 * OUT_F;
    float* __restrict__ or1 = out + (size_t)row1 * OUT_F;

    #pragma unroll
    for (int c = 0; c < 4; ++c) {
        const int o = c * 256 + lane * 4;
        float4 af[RANK];
        #pragma unroll
        for (int r = 0; r < RANK; ++r)
            af[r] = *(const float4*)(at + r * OUT_F + o);

        vfloat4 rv0 = bo[0][c];
        vfloat4 rv1 = bo[1][c];
        #pragma unroll
        for (int r = 0; r < RANK; ++r) {
            rv0.x += acc[0][r] * af[r].x;  rv0.y += acc[0][r] * af[r].y;
            rv0.z += acc[0][r] * af[r].z;  rv0.w += acc[0][r] * af[r].w;
            rv1.x += acc[1][r] * af[r].x;  rv1.y += acc[1][r] * af[r].y;
            rv1.z += acc[1][r] * af[r].z;  rv1.w += acc[1][r] * af[r].w;
        }
        __builtin_nontemporal_store(rv0, (vfloat4*)(or0 + o));
        __builtin_nontemporal_store(rv1, (vfloat4*)(or1 + o));
    }
}

extern "C" void kernel_launch(void* const* d_in, const int* in_sizes, int n_in,
                              void* d_out, int out_size, void* d_ws, size_t ws_size,
                              hipStream_t stream) {
    const float* x        = (const float*)d_in[0];
    const float* base_out = (const float*)d_in[1];
    const float* task_emb = (const float*)d_in[2];
    const float* Wa1      = (const float*)d_in[3];
    const float* ba1      = (const float*)d_in[4];
    const float* Wa2      = (const float*)d_in[5];
    const float* ba2      = (const float*)d_in[6];
    const float* Wb1      = (const float*)d_in[7];
    const float* bb1      = (const float*)d_in[8];
    const float* Wb2      = (const float*)d_in[9];
    const float* bb2      = (const float*)d_in[10];
    float* out = (float*)d_out;

    float* vec_a_t = (float*)d_ws;                        // 4*8192 floats
    float* vec_b   = vec_a_t + 4 * RANK * OUT_F;          // 4*8192 floats

    const int b_eff = in_sizes[0] / IN_F;                 // 8192

    gen_kernel<<<256, 256, 0, stream>>>(task_emb, Wa1, ba1, Wa2, ba2,
                                        Wb1, bb1, Wb2, bb2, vec_a_t, vec_b);
    apply_kernel<<<b_eff / 8, 256, 0, stream>>>(x, base_out, vec_a_t, vec_b, out);
}

// Round 7
// 146.584 us; speedup vs baseline: 1.0041x; 1.0041x over previous
//
#include <hip/hip_runtime.h>
#include <math.h>

#define IN_F   1024
#define OUT_F  1024
#define TASK_D 256
#define RANK   8
#define HID    64
// SCALING = ALPHA / RANK = 1.0 (identity)

typedef float vfloat4 __attribute__((ext_vector_type(4)));

__device__ __forceinline__ float gelu_exact(float v) {
    return 0.5f * v * (1.0f + erff(v * 0.70710678118654752f));
}

// ---------------------------------------------------------------------------
// Kernel 1: generate LoRA tables for all 4 tasks.
//   vec_a_t : [4][RANK][OUT_F]  (TRANSPOSED: a_t[t][r][o] = a[t][o][r])
//   vec_b   : [4][RANK][IN_F]
// ---------------------------------------------------------------------------
__global__ __launch_bounds__(256) void gen_kernel(
    const float* __restrict__ task_emb,
    const float* __restrict__ Wa1, const float* __restrict__ ba1,
    const float* __restrict__ Wa2, const float* __restrict__ ba2,
    const float* __restrict__ Wb1, const float* __restrict__ bb1,
    const float* __restrict__ Wb2, const float* __restrict__ bb2,
    float* __restrict__ vec_a_t, float* __restrict__ vec_b)
{
    const int gen = blockIdx.x >> 7;             // 0 -> a, 1 -> b
    const int blk = blockIdx.x & 127;
    const float* __restrict__ W1 = gen ? Wb1 : Wa1;
    const float* __restrict__ b1 = gen ? bb1 : ba1;
    const float* __restrict__ W2 = gen ? Wb2 : Wa2;
    const float* __restrict__ b2 = gen ? bb2 : ba2;

    __shared__ float hs[4][HID];
    {
        const int j = threadIdx.x >> 2;          // hidden unit 0..63
        const int t = threadIdx.x & 3;           // task 0..3
        const float4* te = (const float4*)(task_emb + t * TASK_D);
        const float4* w  = (const float4*)(W1 + j * TASK_D);
        float acc = 0.f;
        #pragma unroll
        for (int d = 0; d < TASK_D / 4; ++d) {
            float4 a = te[d], b = w[d];
            acc += a.x * b.x + a.y * b.y + a.z * b.z + a.w * b.w;
        }
        hs[t][j] = gelu_exact(acc + b1[j]);
    }
    __syncthreads();

    const int lrow = threadIdx.x >> 2;           // 0..63  (W2 row within block)
    const int q    = threadIdx.x & 3;            // quarter of 64 hidden dims
    const int o    = blk * 64 + lrow;            // W2 row 0..8191

    const float4* w2 = (const float4*)(W2 + (size_t)o * HID + q * 16);
    float acc0 = 0.f, acc1 = 0.f, acc2 = 0.f, acc3 = 0.f;
    #pragma unroll
    for (int k = 0; k < 4; ++k) {
        float4 w = w2[k];
        const int kb = q * 16 + k * 4;
        acc0 += hs[0][kb] * w.x + hs[0][kb+1] * w.y + hs[0][kb+2] * w.z + hs[0][kb+3] * w.w;
        acc1 += hs[1][kb] * w.x + hs[1][kb+1] * w.y + hs[1][kb+2] * w.z + hs[1][kb+3] * w.w;
        acc2 += hs[2][kb] * w.x + hs[2][kb+1] * w.y + hs[2][kb+2] * w.z + hs[2][kb+3] * w.w;
        acc3 += hs[3][kb] * w.x + hs[3][kb+1] * w.y + hs[3][kb+2] * w.z + hs[3][kb+3] * w.w;
    }
    #pragma unroll
    for (int off = 1; off <= 2; off <<= 1) {
        acc0 += __shfl_xor(acc0, off, 64);
        acc1 += __shfl_xor(acc1, off, 64);
        acc2 += __shfl_xor(acc2, off, 64);
        acc3 += __shfl_xor(acc3, off, 64);
    }
    if (q == 0) {
        const float bb = b2[o];
        float v[4] = { acc0 + bb, acc1 + bb, acc2 + bb, acc3 + bb };
        if (gen == 0) {
            const int oo = o >> 3, r = o & 7;    // vec_a row o -> (out oo, rank r)
            #pragma unroll
            for (int t = 0; t < 4; ++t)
                vec_a_t[t * (RANK * OUT_F) + r * OUT_F + oo] = v[t];
        } else {
            #pragma unroll
            for (int t = 0; t < 4; ++t)
                vec_b[t * (RANK * IN_F) + o] = v[t];
        }
    }
}

// ---------------------------------------------------------------------------
// Kernel 2: fused LoRA apply, 4 rows per wave.
// 512 blocks x 256 threads (2 blocks/CU, 8 waves/CU, 64 KB LDS/CU).
// One task per block; vec_b[t] staged in LDS (32 KB).
//   - 8 staging + 16 x float4 loads issued before the single barrier
//   - dots are chunk-outer: each ds_read_b128 of bv feeds 4 rows (16 FMA)
//   - epilogue: all 16 base_out loads issued up front, then chunk-outer
//     af loop (each af chunk feeds 4 rows)
// No nontemporal hints: x/base_out are L3-resident after the harness's
// restore copies (R1 FETCH evidence), nt would bypass that.
// ---------------------------------------------------------------------------
__global__ __launch_bounds__(256, 2) void apply_kernel(
    const float* __restrict__ x, const float* __restrict__ base_out,
    const float* __restrict__ vec_a_t, const float* __restrict__ vec_b,
    float* __restrict__ out)
{
    const int t    = blockIdx.x & 3;             // task
    const int g    = blockIdx.x >> 2;            // 0..127
    const int wave = threadIdx.x >> 6;
    const int lane = threadIdx.x & 63;

    const int jb   = g * 16 + wave * 4;          // row/4 base; rows = t + 4*(jb+i)

    __shared__ float bs[RANK * IN_F];            // 32 KB

    // 1) staging loads (oldest in the vmem queue)
    vfloat4 stage[8];
    {
        const vfloat4* src = (const vfloat4*)(vec_b + (size_t)t * (RANK * IN_F));
        #pragma unroll
        for (int i = 0; i < 8; ++i)
            stage[i] = src[threadIdx.x + 256 * i];
    }

    // 2) x loads for all 4 rows (overlap staging drain)
    float4 xv[4][4];
    #pragma unroll
    for (int i = 0; i < 4; ++i) {
        const float* __restrict__ xr = x + (size_t)(t + 4 * (jb + i)) * IN_F;
        #pragma unroll
        for (int c = 0; c < 4; ++c)
            xv[i][c] = *(const float4*)(xr + c * 256 + lane * 4);
    }

    // 3) LDS fill + barrier
    {
        vfloat4* dst = (vfloat4*)bs;
        #pragma unroll
        for (int i = 0; i < 8; ++i)
            dst[threadIdx.x + 256 * i] = stage[i];
    }
    __syncthreads();

    // Phase 1: chunk-outer rank dots; each bv feeds all 4 rows.
    float acc[4][RANK];
    #pragma unroll
    for (int i = 0; i < 4; ++i)
        #pragma unroll
        for (int r = 0; r < RANK; ++r) acc[i][r] = 0.f;

    #pragma unroll
    for (int c = 0; c < 4; ++c) {
        const int k = c * 256 + lane * 4;
        #pragma unroll
        for (int r = 0; r < RANK; ++r) {
            const float4 bv = *(const float4*)(bs + r * IN_F + k);
            #pragma unroll
            for (int i = 0; i < 4; ++i) {
                acc[i][r] += xv[i][c].x * bv.x + xv[i][c].y * bv.y
                           + xv[i][c].z * bv.z + xv[i][c].w * bv.w;
            }
        }
    }

    // Butterfly reduce the 32 accumulators across the wave.
    #pragma unroll
    for (int off = 32; off > 0; off >>= 1) {
        #pragma unroll
        for (int i = 0; i < 4; ++i)
            #pragma unroll
            for (int r = 0; r < RANK; ++r)
                acc[i][r] += __shfl_xor(acc[i][r], off, 64);
    }

    // Epilogue: issue all base_out loads first (latency hides under the
    // chunk 0..2 compute), then chunk-outer af loop shared across 4 rows.
    const float* __restrict__ at = vec_a_t + (size_t)t * (RANK * OUT_F);

    float4 bo[4][4];
    #pragma unroll
    for (int i = 0; i < 4; ++i) {
        const float* __restrict__ br = base_out + (size_t)(t + 4 * (jb + i)) * OUT_F;
        #pragma unroll
        for (int c = 0; c < 4; ++c)
            bo[i][c] = *(const float4*)(br + c * 256 + lane * 4);
    }

    #pragma unroll
    for (int c = 0; c < 4; ++c) {
        const int o = c * 256 + lane * 4;
        float4 af[RANK];
        #pragma unroll
        for (int r = 0; r < RANK; ++r)
            af[r] = *(const float4*)(at + r * OUT_F + o);

        #pragma unroll
        for (int i = 0; i < 4; ++i) {
            float4 rv = bo[i][c];
            #pragma unroll
            for (int r = 0; r < RANK; ++r) {
                rv.x += acc[i][r] * af[r].x;
                rv.y += acc[i][r] * af[r].y;
                rv.z += acc[i][r] * af[r].z;
                rv.w += acc[i][r] * af[r].w;
            }
            *(float4*)(out + (size_t)(t + 4 * (jb + i)) * OUT_F + o) = rv;
        }
    }
}

extern "C" void kernel_launch(void* const* d_in, const int* in_sizes, int n_in,
                              void* d_out, int out_size, void* d_ws, size_t ws_size,
                              hipStream_t stream) {
    const float* x        = (const float*)d_in[0];
    const float* base_out = (const float*)d_in[1];
    const float* task_emb = (const float*)d_in[2];
    const float* Wa1      = (const float*)d_in[3];
    const float* ba1      = (const float*)d_in[4];
    const float* Wa2      = (const float*)d_in[5];
    const float* ba2      = (const float*)d_in[6];
    const float* Wb1      = (const float*)d_in[7];
    const float* bb1      = (const float*)d_in[8];
    const float* Wb2      = (const float*)d_in[9];
    const float* bb2      = (const float*)d_in[10];
    float* out = (float*)d_out;

    float* vec_a_t = (float*)d_ws;                        // 4*8192 floats
    float* vec_b   = vec_a_t + 4 * RANK * OUT_F;          // 4*8192 floats

    const int b_eff = in_sizes[0] / IN_F;                 // 8192

    gen_kernel<<<256, 256, 0, stream>>>(task_emb, Wa1, ba1, Wa2, ba2,
                                        Wb1, bb1, Wb2, bb2, vec_a_t, vec_b);
    apply_kernel<<<b_eff / 16, 256, 0, stream>>>(x, base_out, vec_a_t, vec_b, out);
}